// Round 2
// baseline (12404.546 us; speedup 1.0000x reference)
//
#include <hip/hip_runtime.h>
#include <cmath>

#define N_NODES 50000
#define N_EDGES 800000
#define NODE_DIM 128
#define EDGE_DIM 100
#define EMB_DIM 92
#define N_GRAPHS 256

__device__ __forceinline__ float softplus_f(float v) {
    return v > 20.0f ? v : log1pf(expf(v));
}
__device__ __forceinline__ float sigmoid_f(float v) {
    return 1.0f / (1.0f + expf(-v));
}

// ---------------------------------------------------------------- edge dist
__global__ void edge_d_kernel(const int* __restrict__ ei, const float* __restrict__ R,
                              float* __restrict__ d) {
    int e = blockIdx.x * blockDim.x + threadIdx.x;
    if (e >= N_EDGES) return;
    int s = ei[e];            // src
    int t = ei[N_EDGES + e];  // dst
    float dx = R[3 * s + 0] - R[3 * t + 0];
    float dy = R[3 * s + 1] - R[3 * t + 1];
    float dz = R[3 * s + 2] - R[3 * t + 2];
    d[e] = sqrtf(dx * dx + dy * dy + dz * dz);
}

// ---------------------------------------------------------------- CSR build
__global__ void deg_kernel(const int* __restrict__ ei, int* __restrict__ deg) {
    int e = blockIdx.x * blockDim.x + threadIdx.x;
    if (e >= N_EDGES) return;
    atomicAdd(&deg[ei[N_EDGES + e]], 1);
}

#define SCAN_B 1024
__global__ void scan_kernel(const int* __restrict__ deg, int* __restrict__ row_ptr) {
    __shared__ int buf[SCAN_B];
    __shared__ int carry;
    int t = threadIdx.x;
    if (t == 0) carry = 0;
    __syncthreads();
    for (int base = 0; base < N_NODES; base += SCAN_B) {
        int c0 = carry;
        int i = base + t;
        int v = (i < N_NODES) ? deg[i] : 0;
        buf[t] = v;
        __syncthreads();
        for (int off = 1; off < SCAN_B; off <<= 1) {
            int add = (t >= off) ? buf[t - off] : 0;
            __syncthreads();
            buf[t] += add;
            __syncthreads();
        }
        if (i < N_NODES) row_ptr[i] = c0 + buf[t] - v;
        __syncthreads();
        if (t == 0) carry = c0 + buf[SCAN_B - 1];
        __syncthreads();
    }
    if (t == 0) row_ptr[N_NODES] = carry;
}

__global__ void fill_kernel(const int* __restrict__ ei, const float* __restrict__ d,
                            const int* __restrict__ row_ptr, int* __restrict__ cnt2,
                            int* __restrict__ s_src, int* __restrict__ s_dst,
                            float* __restrict__ s_d) {
    int e = blockIdx.x * blockDim.x + threadIdx.x;
    if (e >= N_EDGES) return;
    int dst = ei[N_EDGES + e];
    int pos = row_ptr[dst] + atomicAdd(&cnt2[dst], 1);
    s_src[pos] = ei[e];
    s_dst[pos] = dst;
    s_d[pos] = d[e];
}

// ---------------------------------------------------------------- embedding
__global__ void embed_kernel(const int* __restrict__ z, const float* __restrict__ emb,
                             const float* __restrict__ emb_w, const float* __restrict__ emb_b,
                             float* __restrict__ x) {
    __shared__ float er[EMB_DIM * 8];
    __shared__ int zi[8];
    int base = blockIdx.x * 8;
    int t = threadIdx.x;  // 0..127
    if (t < 8) zi[t] = z[base + t];
    __syncthreads();
    for (int idx = t; idx < EMB_DIM * 8; idx += 128) {
        int k = idx >> 3, j = idx & 7;
        er[idx] = emb[zi[j] * EMB_DIM + k];
    }
    __syncthreads();
    float acc[8];
    float bb = emb_b[t];
#pragma unroll
    for (int j = 0; j < 8; j++) acc[j] = bb;
    for (int k = 0; k < EMB_DIM; k++) {
        float w = emb_w[k * NODE_DIM + t];
        float4 ja = *(const float4*)&er[k * 8];
        float4 jb = *(const float4*)&er[k * 8 + 4];
        acc[0] = fmaf(w, ja.x, acc[0]); acc[1] = fmaf(w, ja.y, acc[1]);
        acc[2] = fmaf(w, ja.z, acc[2]); acc[3] = fmaf(w, ja.w, acc[3]);
        acc[4] = fmaf(w, jb.x, acc[4]); acc[5] = fmaf(w, jb.y, acc[5]);
        acc[6] = fmaf(w, jb.z, acc[6]); acc[7] = fmaf(w, jb.w, acc[7]);
    }
#pragma unroll
    for (int j = 0; j < 8; j++) x[(base + j) * NODE_DIM + t] = acc[j];
}

// ---------------------------------------------------------------- node pre-GEMM
__global__ void node_pre_kernel(const float* __restrict__ x, const float* __restrict__ Wl,
                                const float* __restrict__ bl,
                                float* __restrict__ P1, float* __restrict__ P2) {
    __shared__ float xs[NODE_DIM * 8];
    int base = blockIdx.x * 8;
    int t = threadIdx.x;  // 0..255
    for (int idx = t; idx < NODE_DIM * 8; idx += 256) {
        int j = idx >> 7, k = idx & 127;
        xs[k * 8 + j] = x[(base + j) * NODE_DIM + k];
    }
    __syncthreads();
    float a1[8], a2[8];
#pragma unroll
    for (int j = 0; j < 8; j++) { a1[j] = 0.f; a2[j] = 0.f; }
    const float* W1 = Wl;
    const float* W2 = Wl + NODE_DIM * 256;
    for (int k = 0; k < NODE_DIM; k++) {
        float w1 = W1[k * 256 + t];
        float w2 = W2[k * 256 + t];
        float4 ja = *(const float4*)&xs[k * 8];
        float4 jb = *(const float4*)&xs[k * 8 + 4];
        a1[0] = fmaf(w1, ja.x, a1[0]); a1[1] = fmaf(w1, ja.y, a1[1]);
        a1[2] = fmaf(w1, ja.z, a1[2]); a1[3] = fmaf(w1, ja.w, a1[3]);
        a1[4] = fmaf(w1, jb.x, a1[4]); a1[5] = fmaf(w1, jb.y, a1[5]);
        a1[6] = fmaf(w1, jb.z, a1[6]); a1[7] = fmaf(w1, jb.w, a1[7]);
        a2[0] = fmaf(w2, ja.x, a2[0]); a2[1] = fmaf(w2, ja.y, a2[1]);
        a2[2] = fmaf(w2, ja.z, a2[2]); a2[3] = fmaf(w2, ja.w, a2[3]);
        a2[4] = fmaf(w2, jb.x, a2[4]); a2[5] = fmaf(w2, jb.y, a2[5]);
        a2[6] = fmaf(w2, jb.z, a2[6]); a2[7] = fmaf(w2, jb.w, a2[7]);
    }
    float bb = bl[t];
#pragma unroll
    for (int j = 0; j < 8; j++) {
        P1[(base + j) * 256 + t] = a1[j] + bb;
        P2[(base + j) * 256 + t] = a2[j];
    }
}

// ---------------------------------------------------------------- fused edge msg + aggregate
// Block owns dst nodes [64b, 64b+64) and their CSR-contiguous edges. Thread t = output
// channel (t<128: z1[t]; t>=128: z2[t-128]). We[:,t] register-resident. No atomics:
// running-sum per dst flushed on boundary (dst-sorted edges, block-exclusive ranges).
#define EB 8
#define NPB 64
__global__ __launch_bounds__(256, 3) void edge_fused_kernel(
    const int* __restrict__ row_ptr, const int* __restrict__ s_src,
    const int* __restrict__ s_dst, const float* __restrict__ s_d,
    const float* __restrict__ P1, const float* __restrict__ P2,
    const float* __restrict__ We, float* __restrict__ agg) {
    __shared__ float ea[EDGE_DIM * EB];  // 3200 B, [k][j]
    __shared__ float zx[EB * 128];       // 4096 B, z2 exchange
    const float spacing = 6.0f / 99.0f;
    const float coeff = -0.5f / (spacing * spacing);
    int t = threadIdx.x;
    float Wc[EDGE_DIM];
#pragma unroll
    for (int k = 0; k < EDGE_DIM; k++) Wc[k] = We[k * 256 + t];
    int node0 = blockIdx.x * NPB;
    int beg = row_ptr[node0];
    int end = row_ptr[min(node0 + NPB, N_NODES)];
    float run = 0.f;
    int cur_dst = -1;
    for (int i0 = beg; i0 < end; i0 += EB) {
        int m = min(EB, end - i0);
        __syncthreads();  // previous iter's ea/zx readers done
        for (int idx = t; idx < EDGE_DIM * EB; idx += 256) {
            int k = idx >> 3, j = idx & 7;
            float dd = (j < m) ? s_d[i0 + j] : 0.f;
            float df = dd - (float)k * spacing;
            ea[idx] = expf(coeff * df * df);
        }
        __syncthreads();
        float acc[EB];
        int dsts[EB], srcs[EB];
#pragma unroll
        for (int j = 0; j < EB; j++) {
            if (j < m) {
                srcs[j] = s_src[i0 + j];
                dsts[j] = s_dst[i0 + j];
                acc[j] = P1[dsts[j] * 256 + t] + P2[srcs[j] * 256 + t];
            } else {
                srcs[j] = 0; dsts[j] = -1; acc[j] = 0.f;
            }
        }
#pragma unroll
        for (int k = 0; k < EDGE_DIM; k++) {
            float w = Wc[k];
            float4 a = *(const float4*)&ea[k * EB];
            float4 b = *(const float4*)&ea[k * EB + 4];
            acc[0] = fmaf(w, a.x, acc[0]); acc[1] = fmaf(w, a.y, acc[1]);
            acc[2] = fmaf(w, a.z, acc[2]); acc[3] = fmaf(w, a.w, acc[3]);
            acc[4] = fmaf(w, b.x, acc[4]); acc[5] = fmaf(w, b.y, acc[5]);
            acc[6] = fmaf(w, b.z, acc[6]); acc[7] = fmaf(w, b.w, acc[7]);
        }
        if (t >= 128) {
#pragma unroll
            for (int j = 0; j < EB; j++) zx[j * 128 + (t - 128)] = acc[j];
        }
        __syncthreads();
        if (t < 128) {
            for (int j = 0; j < m; j++) {
                float msg = sigmoid_f(acc[j]) * softplus_f(zx[j * 128 + t]);
                if (dsts[j] != cur_dst) {
                    if (cur_dst >= 0) agg[cur_dst * NODE_DIM + t] = run;
                    run = 0.f;
                    cur_dst = dsts[j];
                }
                run += msg;
            }
        }
    }
    if (t < 128 && cur_dst >= 0) agg[cur_dst * NODE_DIM + t] = run;
}

// ---------------------------------------------------------------- layernorm + residual + softplus
__global__ void ln_kernel(const float* __restrict__ agg, const float* __restrict__ g,
                          const float* __restrict__ b, float* __restrict__ x) {
    int n = blockIdx.x, c = threadIdx.x;
    __shared__ float s1[128], s2[128];
    float a = agg[n * 128 + c];
    s1[c] = a;
    s2[c] = a * a;
    __syncthreads();
    for (int off = 64; off > 0; off >>= 1) {
        if (c < off) { s1[c] += s1[c + off]; s2[c] += s2[c + off]; }
        __syncthreads();
    }
    float mu = s1[0] * (1.0f / 128.0f);
    float var = s2[0] * (1.0f / 128.0f) - mu * mu;
    float rstd = rsqrtf(fmaxf(var, 0.f) + 1e-5f);
    float xv = x[n * 128 + c];
    x[n * 128 + c] = softplus_f((a - mu) * rstd * g[c] + b[c] + xv);
}

// ---------------------------------------------------------------- global mean pool (scatter)
__global__ void pool_kernel(const float* __restrict__ x, const int* __restrict__ batch,
                            float* __restrict__ mol, float* __restrict__ cnt) {
    int i = blockIdx.x * blockDim.x + threadIdx.x;
    if (i >= N_NODES * 128) return;
    int n = i >> 7, c = i & 127;
    int g = batch[n];
    atomicAdd(&mol[g * 128 + c], x[i]);
    if (c == 0) atomicAdd(&cnt[g], 1.0f);
}

// ---------------------------------------------------------------- MLP head
__global__ void head_kernel(const float* __restrict__ mol, const float* __restrict__ cnt,
                            const float* __restrict__ cfc_w, const float* __restrict__ cfc_b,
                            const float* __restrict__ fc_w, const float* __restrict__ fc_b,
                            const float* __restrict__ out_w, const float* __restrict__ out_b,
                            float* __restrict__ out) {
    int g = blockIdx.x, c = threadIdx.x;
    __shared__ float h[128], h2[128];
    float denom = fmaxf(cnt[g], 1.0f);
    h[c] = mol[g * 128 + c] / denom;
    __syncthreads();
    float acc = cfc_b[c];
    for (int k = 0; k < 128; k++) acc = fmaf(h[k], cfc_w[k * 128 + c], acc);
    h2[c] = softplus_f(acc);
    __syncthreads();
    for (int l = 0; l < 2; l++) {
        const float* W = fc_w + l * 128 * 128;
        acc = fc_b[l * 128 + c];
        for (int k = 0; k < 128; k++) acc = fmaf(h2[k], W[k * 128 + c], acc);
        __syncthreads();
        h2[c] = softplus_f(acc);
        __syncthreads();
    }
    h[c] = h2[c] * out_w[c];
    __syncthreads();
    for (int off = 64; off > 0; off >>= 1) {
        if (c < off) h[c] += h[c + off];
        __syncthreads();
    }
    if (c == 0) out[g] = h[0] + out_b[0];
}

// ---------------------------------------------------------------- launcher
extern "C" void kernel_launch(void* const* d_in, const int* in_sizes, int n_in,
                              void* d_out, int out_size, void* d_ws, size_t ws_size,
                              hipStream_t stream) {
    const int*   z      = (const int*)d_in[0];
    const float* R      = (const float*)d_in[1];
    const int*   ei     = (const int*)d_in[2];
    const int*   batch  = (const int*)d_in[3];
    const float* emb    = (const float*)d_in[4];
    const float* emb_w  = (const float*)d_in[5];
    const float* emb_b  = (const float*)d_in[6];
    const float* conv_w = (const float*)d_in[7];
    const float* conv_b = (const float*)d_in[8];
    const float* ln_g   = (const float*)d_in[9];
    const float* ln_b   = (const float*)d_in[10];
    const float* cfc_w  = (const float*)d_in[11];
    const float* cfc_b  = (const float*)d_in[12];
    const float* fc_w   = (const float*)d_in[13];
    const float* fc_b   = (const float*)d_in[14];
    const float* out_w  = (const float*)d_in[15];
    const float* out_b  = (const float*)d_in[16];
    float* out = (float*)d_out;

    float* ws    = (float*)d_ws;
    float* dbuf  = ws;                   // 800,000
    float* x     = dbuf + 800000;        // 6,400,000
    float* agg   = x + 6400000;          // 6,400,000
    float* P1    = agg + 6400000;        // 12,800,000
    float* P2    = P1 + 12800000;        // 12,800,000
    float* mol   = P2 + 12800000;        // 32,768
    float* cntv  = mol + 32768;          // 256
    float* s_d   = cntv + 256;           // 800,000
    int* deg     = (int*)(s_d + 800000); // 50,000
    int* cnt2    = deg + 50000;          // 50,000
    int* row_ptr = cnt2 + 50000;         // 50,001
    int* s_src   = row_ptr + 50001;      // 800,000
    int* s_dst   = s_src + 800000;       // 800,000

    // distances + CSR (by dst) once per call
    edge_d_kernel<<<(N_EDGES + 255) / 256, 256, 0, stream>>>(ei, R, dbuf);
    hipMemsetAsync(deg, 0, (size_t)100000 * 4, stream);  // deg + cnt2
    deg_kernel<<<(N_EDGES + 255) / 256, 256, 0, stream>>>(ei, deg);
    scan_kernel<<<1, SCAN_B, 0, stream>>>(deg, row_ptr);
    fill_kernel<<<(N_EDGES + 255) / 256, 256, 0, stream>>>(ei, dbuf, row_ptr, cnt2,
                                                           s_src, s_dst, s_d);

    embed_kernel<<<N_NODES / 8, 128, 0, stream>>>(z, emb, emb_w, emb_b, x);
    int nblk = (N_NODES + NPB - 1) / NPB;  // 782
    for (int l = 0; l < 3; l++) {
        const float* Wl = conv_w + (size_t)l * 356 * 256;
        node_pre_kernel<<<N_NODES / 8, 256, 0, stream>>>(x, Wl, conv_b + l * 256, P1, P2);
        hipMemsetAsync(agg, 0, (size_t)6400000 * 4, stream);
        edge_fused_kernel<<<nblk, 256, 0, stream>>>(row_ptr, s_src, s_dst, s_d,
                                                    P1, P2, Wl + 256 * 256, agg);
        ln_kernel<<<N_NODES, 128, 0, stream>>>(agg, ln_g + l * 128, ln_b + l * 128, x);
    }
    hipMemsetAsync(mol, 0, (size_t)(32768 + 256) * 4, stream);
    pool_kernel<<<(N_NODES * 128 + 255) / 256, 256, 0, stream>>>(x, batch, mol, cntv);
    head_kernel<<<N_GRAPHS, 128, 0, stream>>>(mol, cntv, cfc_w, cfc_b, fc_w, fc_b,
                                              out_w, out_b, out);
}

// Round 3
// 2460.955 us; speedup vs baseline: 5.0405x; 5.0405x over previous
//
#include <hip/hip_runtime.h>
#include <hip/hip_bf16.h>
#include <cmath>

#define N_NODES 50000
#define N_EDGES 800000
#define NODE_DIM 128
#define EDGE_DIM 100
#define EMB_DIM 92
#define N_GRAPHS 256

__device__ __forceinline__ float softplus_f(float v) {
    return v > 20.0f ? v : log1pf(__expf(v));
}
__device__ __forceinline__ float sigmoid_f(float v) {
    return 1.0f / (1.0f + __expf(-v));
}

// ---------------------------------------------------------------- edge dist
__global__ void edge_d_kernel(const int* __restrict__ ei, const float* __restrict__ R,
                              float* __restrict__ d) {
    int e = blockIdx.x * blockDim.x + threadIdx.x;
    if (e >= N_EDGES) return;
    int s = ei[e];
    int t = ei[N_EDGES + e];
    float dx = R[3 * s + 0] - R[3 * t + 0];
    float dy = R[3 * s + 1] - R[3 * t + 1];
    float dz = R[3 * s + 2] - R[3 * t + 2];
    d[e] = sqrtf(dx * dx + dy * dy + dz * dz);
}

// ---------------------------------------------------------------- CSR build
__global__ void deg_kernel(const int* __restrict__ ei, int* __restrict__ deg) {
    int e = blockIdx.x * blockDim.x + threadIdx.x;
    if (e >= N_EDGES) return;
    atomicAdd(&deg[ei[N_EDGES + e]], 1);
}

#define SB 1024
__global__ void scan1_kernel(const int* __restrict__ deg, int* __restrict__ rp,
                             int* __restrict__ bsum) {
    __shared__ int buf[SB];
    int b = blockIdx.x, t = threadIdx.x, i = b * SB + t;
    int v = (i < N_NODES) ? deg[i] : 0;
    buf[t] = v;
    __syncthreads();
    for (int off = 1; off < SB; off <<= 1) {
        int a = (t >= off) ? buf[t - off] : 0;
        __syncthreads();
        buf[t] += a;
        __syncthreads();
    }
    if (i < N_NODES) rp[i] = buf[t] - v;  // exclusive, block-local
    if (t == SB - 1) bsum[b] = buf[t];
}
__global__ void scan2_kernel(int* __restrict__ bsum, int n) {
    if (threadIdx.x == 0) {
        int s = 0;
        for (int i = 0; i < n; i++) { int v = bsum[i]; bsum[i] = s; s += v; }
    }
}
__global__ void scan3_kernel(int* __restrict__ rp, const int* __restrict__ bsum) {
    int i = blockIdx.x * SB + threadIdx.x;
    if (i < N_NODES) rp[i] += bsum[blockIdx.x];
    if (i == 0) rp[N_NODES] = N_EDGES;
}

__global__ void fill_kernel(const int* __restrict__ ei, const float* __restrict__ d,
                            const int* __restrict__ row_ptr, int* __restrict__ cnt2,
                            int* __restrict__ s_src, int* __restrict__ s_dst,
                            float* __restrict__ s_d) {
    int e = blockIdx.x * blockDim.x + threadIdx.x;
    if (e >= N_EDGES) return;
    int dst = ei[N_EDGES + e];
    int pos = row_ptr[dst] + atomicAdd(&cnt2[dst], 1);
    s_src[pos] = ei[e];
    s_dst[pos] = dst;
    s_d[pos] = d[e];
}

// ---------------------------------------------------------------- We -> bf16 (all 3 layers)
__global__ void wcvt_kernel(const float* __restrict__ conv_w, __hip_bfloat16* __restrict__ Webf) {
    int i = blockIdx.x * 256 + threadIdx.x;  // 3*100*256 = 76800
    if (i >= 3 * EDGE_DIM * 256) return;
    int l = i / (EDGE_DIM * 256), r = i - l * (EDGE_DIM * 256);
    Webf[i] = (__hip_bfloat16)conv_w[(size_t)l * 356 * 256 + 256 * 256 + r];
}

// ---------------------------------------------------------------- embedding
__global__ void embed_kernel(const int* __restrict__ z, const float* __restrict__ emb,
                             const float* __restrict__ emb_w, const float* __restrict__ emb_b,
                             float* __restrict__ x) {
    __shared__ float er[EMB_DIM * 8];
    __shared__ int zi[8];
    int base = blockIdx.x * 8;
    int t = threadIdx.x;  // 0..127
    if (t < 8) zi[t] = z[base + t];
    __syncthreads();
    for (int idx = t; idx < EMB_DIM * 8; idx += 128) {
        int k = idx >> 3, j = idx & 7;
        er[idx] = emb[zi[j] * EMB_DIM + k];
    }
    __syncthreads();
    float acc[8];
    float bb = emb_b[t];
#pragma unroll
    for (int j = 0; j < 8; j++) acc[j] = bb;
    for (int k = 0; k < EMB_DIM; k++) {
        float w = emb_w[k * NODE_DIM + t];
        float4 ja = *(const float4*)&er[k * 8];
        float4 jb = *(const float4*)&er[k * 8 + 4];
        acc[0] = fmaf(w, ja.x, acc[0]); acc[1] = fmaf(w, ja.y, acc[1]);
        acc[2] = fmaf(w, ja.z, acc[2]); acc[3] = fmaf(w, ja.w, acc[3]);
        acc[4] = fmaf(w, jb.x, acc[4]); acc[5] = fmaf(w, jb.y, acc[5]);
        acc[6] = fmaf(w, jb.z, acc[6]); acc[7] = fmaf(w, jb.w, acc[7]);
    }
#pragma unroll
    for (int j = 0; j < 8; j++) x[(base + j) * NODE_DIM + t] = acc[j];
}

// ---------------------------------------------------------------- node pre-GEMM
__global__ void node_pre_kernel(const float* __restrict__ x, const float* __restrict__ Wl,
                                const float* __restrict__ bl,
                                float* __restrict__ P1, float* __restrict__ P2) {
    __shared__ float xs[NODE_DIM * 8];
    int base = blockIdx.x * 8;
    int t = threadIdx.x;  // 0..255
    for (int idx = t; idx < NODE_DIM * 8; idx += 256) {
        int j = idx >> 7, k = idx & 127;
        xs[k * 8 + j] = x[(base + j) * NODE_DIM + k];
    }
    __syncthreads();
    float a1[8], a2[8];
#pragma unroll
    for (int j = 0; j < 8; j++) { a1[j] = 0.f; a2[j] = 0.f; }
    const float* W1 = Wl;
    const float* W2 = Wl + NODE_DIM * 256;
    for (int k = 0; k < NODE_DIM; k++) {
        float w1 = W1[k * 256 + t];
        float w2 = W2[k * 256 + t];
        float4 ja = *(const float4*)&xs[k * 8];
        float4 jb = *(const float4*)&xs[k * 8 + 4];
        a1[0] = fmaf(w1, ja.x, a1[0]); a1[1] = fmaf(w1, ja.y, a1[1]);
        a1[2] = fmaf(w1, ja.z, a1[2]); a1[3] = fmaf(w1, ja.w, a1[3]);
        a1[4] = fmaf(w1, jb.x, a1[4]); a1[5] = fmaf(w1, jb.y, a1[5]);
        a1[6] = fmaf(w1, jb.z, a1[6]); a1[7] = fmaf(w1, jb.w, a1[7]);
        a2[0] = fmaf(w2, ja.x, a2[0]); a2[1] = fmaf(w2, ja.y, a2[1]);
        a2[2] = fmaf(w2, ja.z, a2[2]); a2[3] = fmaf(w2, ja.w, a2[3]);
        a2[4] = fmaf(w2, jb.x, a2[4]); a2[5] = fmaf(w2, jb.y, a2[5]);
        a2[6] = fmaf(w2, jb.z, a2[6]); a2[7] = fmaf(w2, jb.w, a2[7]);
    }
    float bb = bl[t];
#pragma unroll
    for (int j = 0; j < 8; j++) {
        P1[(base + j) * 256 + t] = a1[j] + bb;
        P2[(base + j) * 256 + t] = a2[j];
    }
}

// ---------------------------------------------------------------- edge msg v3
// dst-sorted edges, contiguous range per block, 32-edge chunks. Sparse 12-tap
// gaussian window (taps beyond 5.5 sigma < 3e-7, negligible). We in LDS as bf16
// (51.2 KB -> 2 blocks/CU). Per-chunk LDS segmented reduce, few atomics.
#define NT 12
#define EG2 32
#define EPB 256
__global__ __launch_bounds__(256, 2) void edge_fused2(
    const int* __restrict__ s_src, const int* __restrict__ s_dst,
    const float* __restrict__ s_d,
    const float* __restrict__ P1, const float* __restrict__ P2,
    const __hip_bfloat16* __restrict__ Webf,  // [100][256] this layer
    float* __restrict__ agg) {
    __shared__ __hip_bfloat16 WeL[EDGE_DIM * 256];  // 51200 B
    __shared__ float msgL[EG2 * 128];               // 16384 B
    __shared__ float eaL[EG2 * NT];                 // 1536 B
    __shared__ int dstL[EG2];
    __shared__ int srcL[EG2];
    __shared__ float dL_[EG2];
    __shared__ int k0L[EG2];
    int t = threadIdx.x;
    {  // stage We once per block: 51200 B = 3200 x 16B
        const float4* s4 = (const float4*)Webf;
        float4* d4 = (float4*)WeL;
        for (int i = t; i < 3200; i += 256) d4[i] = s4[i];
    }
    const float sp_ = 6.0f / 99.0f;
    const float inv_s = 99.0f / 6.0f;
    const float coeff = -0.5f * inv_s * inv_s;
    int w = t >> 6, lane = t & 63, h = lane >> 5, q = lane & 31;
    int base0 = blockIdx.x * EPB;
    int bend = min(base0 + EPB, N_EDGES);
    for (int base = base0; base < bend; base += EG2) {
        int m = min(EG2, bend - base);
        __syncthreads();  // We staged / prev chunk LDS readers done
        if (t < EG2) {
            if (t < m) {
                float dv = s_d[base + t];
                dstL[t] = s_dst[base + t];
                srcL[t] = s_src[base + t];
                dL_[t] = dv;
                int k0;
                if (dv > 6.34f) k0 = -1;
                else {
                    k0 = (int)ceilf(dv * inv_s - 5.5f);
                    k0 = max(0, min(EDGE_DIM - NT, k0));
                }
                k0L[t] = k0;
            } else {
                dstL[t] = -1; srcL[t] = 0; dL_[t] = 1e9f; k0L[t] = -1;
            }
        }
        __syncthreads();
        // edge_attr taps
        for (int idx = t; idx < EG2 * NT; idx += 256) {
            int j = idx / NT, i = idx - j * NT;
            int k0 = k0L[j];
            float v = 0.f;
            if (k0 >= 0) {
                float df = dL_[j] - (float)(k0 + i) * sp_;
                v = __expf(coeff * df * df);
            }
            eaL[idx] = v;
        }
        // gather P1[dst]+P2[src] (float4, round-1 pattern)
        float4 a1[4], a2[4];
        int ds_[4], k0_[4];
#pragma unroll
        for (int mm = 0; mm < 4; mm++) {
            int j = w * 8 + h * 4 + mm;
            int dd = dstL[j], sc = srcL[j];
            ds_[mm] = dd; k0_[mm] = k0L[j];
            int dr = (dd < 0) ? 0 : dd;
            float4 p1a = *(const float4*)&P1[(size_t)dr * 256 + 4 * q];
            float4 p2a = *(const float4*)&P2[(size_t)sc * 256 + 4 * q];
            float4 p1b = *(const float4*)&P1[(size_t)dr * 256 + 128 + 4 * q];
            float4 p2b = *(const float4*)&P2[(size_t)sc * 256 + 128 + 4 * q];
            a1[mm] = make_float4(p1a.x + p2a.x, p1a.y + p2a.y, p1a.z + p2a.z, p1a.w + p2a.w);
            a2[mm] = make_float4(p1b.x + p2b.x, p1b.y + p2b.y, p1b.z + p2b.z, p1b.w + p2b.w);
        }
        __syncthreads();  // eaL ready
        // sparse tap FMAs
#pragma unroll
        for (int mm = 0; mm < 4; mm++) {
            int j = w * 8 + h * 4 + mm;
            int k0 = k0_[mm];
            if (k0 >= 0) {
#pragma unroll
                for (int i = 0; i < NT; i++) {
                    float e = eaL[j * NT + i];
                    const uint2* row = (const uint2*)&WeL[(k0 + i) * 256];
                    uint2 u1 = row[q];
                    uint2 u2 = row[32 + q];
                    float f0 = __uint_as_float(u1.x << 16);
                    float f1 = __uint_as_float(u1.x & 0xffff0000u);
                    float f2 = __uint_as_float(u1.y << 16);
                    float f3 = __uint_as_float(u1.y & 0xffff0000u);
                    a1[mm].x = fmaf(f0, e, a1[mm].x);
                    a1[mm].y = fmaf(f1, e, a1[mm].y);
                    a1[mm].z = fmaf(f2, e, a1[mm].z);
                    a1[mm].w = fmaf(f3, e, a1[mm].w);
                    float g0 = __uint_as_float(u2.x << 16);
                    float g1 = __uint_as_float(u2.x & 0xffff0000u);
                    float g2 = __uint_as_float(u2.y << 16);
                    float g3 = __uint_as_float(u2.y & 0xffff0000u);
                    a2[mm].x = fmaf(g0, e, a2[mm].x);
                    a2[mm].y = fmaf(g1, e, a2[mm].y);
                    a2[mm].z = fmaf(g2, e, a2[mm].z);
                    a2[mm].w = fmaf(g3, e, a2[mm].w);
                }
            }
        }
        // epilogue -> msg LDS
#pragma unroll
        for (int mm = 0; mm < 4; mm++) {
            int j = w * 8 + h * 4 + mm;
            float4 z1 = a1[mm], z2 = a2[mm], mg;
            mg.x = sigmoid_f(z1.x) * softplus_f(z2.x);
            mg.y = sigmoid_f(z1.y) * softplus_f(z2.y);
            mg.z = sigmoid_f(z1.z) * softplus_f(z2.z);
            mg.w = sigmoid_f(z1.w) * softplus_f(z2.w);
            if (ds_[mm] < 0) mg = make_float4(0.f, 0.f, 0.f, 0.f);
            *(float4*)&msgL[j * 128 + 4 * q] = mg;
        }
        __syncthreads();
        // segmented reduce: thread = (channel, edge-half); dst uniform per wave
        int c = t & 127, eb = (t >> 7) * 16, ee = eb + 16;
        float run = 0.f;
        int cur = -1;
        for (int e = eb; e < ee; e++) {
            int dd = dstL[e];
            float v = msgL[e * 128 + c];
            if (dd != cur) {
                if (cur >= 0) atomicAdd(&agg[(size_t)cur * NODE_DIM + c], run);
                run = 0.f;
                cur = dd;
            }
            if (dd >= 0) run += v;
        }
        if (cur >= 0) atomicAdd(&agg[(size_t)cur * NODE_DIM + c], run);
    }
}

// ---------------------------------------------------------------- layernorm + residual + softplus
__global__ void ln_kernel(const float* __restrict__ agg, const float* __restrict__ g,
                          const float* __restrict__ b, float* __restrict__ x) {
    int n = blockIdx.x, c = threadIdx.x;
    __shared__ float s1[128], s2[128];
    float a = agg[n * 128 + c];
    s1[c] = a;
    s2[c] = a * a;
    __syncthreads();
    for (int off = 64; off > 0; off >>= 1) {
        if (c < off) { s1[c] += s1[c + off]; s2[c] += s2[c + off]; }
        __syncthreads();
    }
    float mu = s1[0] * (1.0f / 128.0f);
    float var = s2[0] * (1.0f / 128.0f) - mu * mu;
    float rstd = rsqrtf(fmaxf(var, 0.f) + 1e-5f);
    float xv = x[n * 128 + c];
    x[n * 128 + c] = softplus_f((a - mu) * rstd * g[c] + b[c] + xv);
}

// ---------------------------------------------------------------- global mean pool
__global__ void pool_kernel(const float* __restrict__ x, const int* __restrict__ batch,
                            float* __restrict__ mol, float* __restrict__ cnt) {
    int i = blockIdx.x * blockDim.x + threadIdx.x;
    if (i >= N_NODES * 128) return;
    int n = i >> 7, c = i & 127;
    int g = batch[n];
    atomicAdd(&mol[g * 128 + c], x[i]);
    if (c == 0) atomicAdd(&cnt[g], 1.0f);
}

// ---------------------------------------------------------------- MLP head
__global__ void head_kernel(const float* __restrict__ mol, const float* __restrict__ cnt,
                            const float* __restrict__ cfc_w, const float* __restrict__ cfc_b,
                            const float* __restrict__ fc_w, const float* __restrict__ fc_b,
                            const float* __restrict__ out_w, const float* __restrict__ out_b,
                            float* __restrict__ out) {
    int g = blockIdx.x, c = threadIdx.x;
    __shared__ float h[128], h2[128];
    float denom = fmaxf(cnt[g], 1.0f);
    h[c] = mol[g * 128 + c] / denom;
    __syncthreads();
    float acc = cfc_b[c];
    for (int k = 0; k < 128; k++) acc = fmaf(h[k], cfc_w[k * 128 + c], acc);
    h2[c] = softplus_f(acc);
    __syncthreads();
    for (int l = 0; l < 2; l++) {
        const float* W = fc_w + l * 128 * 128;
        acc = fc_b[l * 128 + c];
        for (int k = 0; k < 128; k++) acc = fmaf(h2[k], W[k * 128 + c], acc);
        __syncthreads();
        h2[c] = softplus_f(acc);
        __syncthreads();
    }
    h[c] = h2[c] * out_w[c];
    __syncthreads();
    for (int off = 64; off > 0; off >>= 1) {
        if (c < off) h[c] += h[c + off];
        __syncthreads();
    }
    if (c == 0) out[g] = h[0] + out_b[0];
}

// ---------------------------------------------------------------- launcher
extern "C" void kernel_launch(void* const* d_in, const int* in_sizes, int n_in,
                              void* d_out, int out_size, void* d_ws, size_t ws_size,
                              hipStream_t stream) {
    const int*   z      = (const int*)d_in[0];
    const float* R      = (const float*)d_in[1];
    const int*   ei     = (const int*)d_in[2];
    const int*   batch  = (const int*)d_in[3];
    const float* emb    = (const float*)d_in[4];
    const float* emb_w  = (const float*)d_in[5];
    const float* emb_b  = (const float*)d_in[6];
    const float* conv_w = (const float*)d_in[7];
    const float* conv_b = (const float*)d_in[8];
    const float* ln_g   = (const float*)d_in[9];
    const float* ln_b   = (const float*)d_in[10];
    const float* cfc_w  = (const float*)d_in[11];
    const float* cfc_b  = (const float*)d_in[12];
    const float* fc_w   = (const float*)d_in[13];
    const float* fc_b   = (const float*)d_in[14];
    const float* out_w  = (const float*)d_in[15];
    const float* out_b  = (const float*)d_in[16];
    float* out = (float*)d_out;

    float* ws    = (float*)d_ws;
    float* dbuf  = ws;                    // 800,000
    float* x     = dbuf + 800000;         // 6,400,000
    float* agg   = x + 6400000;           // 6,400,000
    float* P1    = agg + 6400000;         // 12,800,000
    float* P2    = P1 + 12800000;         // 12,800,000
    float* mol   = P2 + 12800000;         // 32,768
    float* cntv  = mol + 32768;           // 256
    float* s_d   = cntv + 256;            // 800,000
    int* deg     = (int*)(s_d + 800000);  // 50,000
    int* cnt2    = deg + 50000;           // 50,000
    int* row_ptr = cnt2 + 50000;          // 50,001
    int* s_src   = row_ptr + 50001;       // 800,000
    int* s_dst   = s_src + 800000;        // 800,000
    int* bsum    = s_dst + 800000;        // 64
    __hip_bfloat16* Webf = (__hip_bfloat16*)(bsum + 64);  // 76,800 bf16

    // distances + dst-sorted CSR once per call
    edge_d_kernel<<<(N_EDGES + 255) / 256, 256, 0, stream>>>(ei, R, dbuf);
    hipMemsetAsync(deg, 0, (size_t)100000 * 4, stream);  // deg + cnt2
    deg_kernel<<<(N_EDGES + 255) / 256, 256, 0, stream>>>(ei, deg);
    int nsb = (N_NODES + SB - 1) / SB;  // 49
    scan1_kernel<<<nsb, SB, 0, stream>>>(deg, row_ptr, bsum);
    scan2_kernel<<<1, 64, 0, stream>>>(bsum, nsb);
    scan3_kernel<<<nsb, SB, 0, stream>>>(row_ptr, bsum);
    fill_kernel<<<(N_EDGES + 255) / 256, 256, 0, stream>>>(ei, dbuf, row_ptr, cnt2,
                                                           s_src, s_dst, s_d);
    wcvt_kernel<<<(3 * EDGE_DIM * 256 + 255) / 256, 256, 0, stream>>>(conv_w, Webf);

    embed_kernel<<<N_NODES / 8, 128, 0, stream>>>(z, emb, emb_w, emb_b, x);
    int nblk = (N_EDGES + EPB - 1) / EPB;  // 3125
    for (int l = 0; l < 3; l++) {
        const float* Wl = conv_w + (size_t)l * 356 * 256;
        node_pre_kernel<<<N_NODES / 8, 256, 0, stream>>>(x, Wl, conv_b + l * 256, P1, P2);
        hipMemsetAsync(agg, 0, (size_t)6400000 * 4, stream);
        edge_fused2<<<nblk, 256, 0, stream>>>(s_src, s_dst, s_d, P1, P2,
                                              Webf + (size_t)l * EDGE_DIM * 256, agg);
        ln_kernel<<<N_NODES, 128, 0, stream>>>(agg, ln_g + l * 128, ln_b + l * 128, x);
    }
    hipMemsetAsync(mol, 0, (size_t)(32768 + 256) * 4, stream);
    pool_kernel<<<(N_NODES * 128 + 255) / 256, 256, 0, stream>>>(x, batch, mol, cntv);
    head_kernel<<<N_GRAPHS, 128, 0, stream>>>(mol, cntv, cfc_w, cfc_b, fc_w, fc_b,
                                              out_w, out_b, out);
}

// Round 4
// 1643.798 us; speedup vs baseline: 7.5463x; 1.4971x over previous
//
#include <hip/hip_runtime.h>
#include <hip/hip_bf16.h>
#include <cmath>

#define N_NODES 50000
#define N_EDGES 800000
#define NODE_DIM 128
#define EDGE_DIM 100
#define EMB_DIM 92
#define N_GRAPHS 256

__device__ __forceinline__ float softplus_f(float v) {
    // fast: log(1+exp(v)); abs err ~1e-6, fine vs 4.7e-3 threshold
    return v > 20.0f ? v : __logf(1.0f + __expf(v));
}
__device__ __forceinline__ float sigmoid_f(float v) {
    return 1.0f / (1.0f + __expf(-v));
}

// ---------------------------------------------------------------- edge dist
__global__ void edge_d_kernel(const int* __restrict__ ei, const float* __restrict__ R,
                              float* __restrict__ d) {
    int e = blockIdx.x * blockDim.x + threadIdx.x;
    if (e >= N_EDGES) return;
    int s = ei[e];
    int t = ei[N_EDGES + e];
    float dx = R[3 * s + 0] - R[3 * t + 0];
    float dy = R[3 * s + 1] - R[3 * t + 1];
    float dz = R[3 * s + 2] - R[3 * t + 2];
    d[e] = sqrtf(dx * dx + dy * dy + dz * dz);
}

// ---------------------------------------------------------------- CSR build
__global__ void deg_kernel(const int* __restrict__ ei, int* __restrict__ deg) {
    int e = blockIdx.x * blockDim.x + threadIdx.x;
    if (e >= N_EDGES) return;
    atomicAdd(&deg[ei[N_EDGES + e]], 1);
}

#define SB 1024
__global__ void scan1_kernel(const int* __restrict__ deg, int* __restrict__ rp,
                             int* __restrict__ bsum) {
    __shared__ int buf[SB];
    int b = blockIdx.x, t = threadIdx.x, i = b * SB + t;
    int v = (i < N_NODES) ? deg[i] : 0;
    buf[t] = v;
    __syncthreads();
    for (int off = 1; off < SB; off <<= 1) {
        int a = (t >= off) ? buf[t - off] : 0;
        __syncthreads();
        buf[t] += a;
        __syncthreads();
    }
    if (i < N_NODES) rp[i] = buf[t] - v;
    if (t == SB - 1) bsum[b] = buf[t];
}
__global__ void scan2_kernel(int* __restrict__ bsum, int n) {
    if (threadIdx.x == 0) {
        int s = 0;
        for (int i = 0; i < n; i++) { int v = bsum[i]; bsum[i] = s; s += v; }
    }
}
__global__ void scan3_kernel(int* __restrict__ rp, const int* __restrict__ bsum) {
    int i = blockIdx.x * SB + threadIdx.x;
    if (i < N_NODES) rp[i] += bsum[blockIdx.x];
    if (i == 0) rp[N_NODES] = N_EDGES;
}

__global__ void fill_kernel(const int* __restrict__ ei, const float* __restrict__ d,
                            const int* __restrict__ row_ptr, int* __restrict__ cnt2,
                            int* __restrict__ s_src, int* __restrict__ s_dst,
                            float* __restrict__ s_d) {
    int e = blockIdx.x * blockDim.x + threadIdx.x;
    if (e >= N_EDGES) return;
    int dst = ei[N_EDGES + e];
    int pos = row_ptr[dst] + atomicAdd(&cnt2[dst], 1);
    s_src[pos] = ei[e];
    s_dst[pos] = dst;
    s_d[pos] = d[e];
}

// ---------------------------------------------------------------- We -> bf16
__global__ void wcvt_kernel(const float* __restrict__ conv_w, __hip_bfloat16* __restrict__ Webf) {
    int i = blockIdx.x * 256 + threadIdx.x;
    if (i >= 3 * EDGE_DIM * 256) return;
    int l = i / (EDGE_DIM * 256), r = i - l * (EDGE_DIM * 256);
    Webf[i] = (__hip_bfloat16)conv_w[(size_t)l * 356 * 256 + 256 * 256 + r];
}

// ---------------------------------------------------------------- embedding
__global__ void embed_kernel(const int* __restrict__ z, const float* __restrict__ emb,
                             const float* __restrict__ emb_w, const float* __restrict__ emb_b,
                             float* __restrict__ x) {
    __shared__ float er[EMB_DIM * 8];
    __shared__ int zi[8];
    int base = blockIdx.x * 8;
    int t = threadIdx.x;  // 0..127
    if (t < 8) zi[t] = z[base + t];
    __syncthreads();
    for (int idx = t; idx < EMB_DIM * 8; idx += 128) {
        int k = idx >> 3, j = idx & 7;
        er[idx] = emb[zi[j] * EMB_DIM + k];
    }
    __syncthreads();
    float acc[8];
    float bb = emb_b[t];
#pragma unroll
    for (int j = 0; j < 8; j++) acc[j] = bb;
    for (int k = 0; k < EMB_DIM; k++) {
        float w = emb_w[k * NODE_DIM + t];
        float4 ja = *(const float4*)&er[k * 8];
        float4 jb = *(const float4*)&er[k * 8 + 4];
        acc[0] = fmaf(w, ja.x, acc[0]); acc[1] = fmaf(w, ja.y, acc[1]);
        acc[2] = fmaf(w, ja.z, acc[2]); acc[3] = fmaf(w, ja.w, acc[3]);
        acc[4] = fmaf(w, jb.x, acc[4]); acc[5] = fmaf(w, jb.y, acc[5]);
        acc[6] = fmaf(w, jb.z, acc[6]); acc[7] = fmaf(w, jb.w, acc[7]);
    }
#pragma unroll
    for (int j = 0; j < 8; j++) x[(base + j) * NODE_DIM + t] = acc[j];
}

// ---------------------------------------------------------------- node pre-GEMM (16 nodes/block)
#define NPB2 16
__global__ __launch_bounds__(256) void node_pre_kernel(
    const float* __restrict__ x, const float* __restrict__ Wl,
    const float* __restrict__ bl, float* __restrict__ P1, float* __restrict__ P2) {
    __shared__ float xs[NODE_DIM * NPB2];  // [k][j] 8 KB
    int base = blockIdx.x * NPB2;
    int t = threadIdx.x;  // 0..255 output channel
    for (int idx = t; idx < NODE_DIM * NPB2; idx += 256) {
        int j = idx >> 7, k = idx & 127;
        xs[k * NPB2 + j] = x[(base + j) * NODE_DIM + k];
    }
    __syncthreads();
    float a1[NPB2], a2[NPB2];
#pragma unroll
    for (int j = 0; j < NPB2; j++) { a1[j] = 0.f; a2[j] = 0.f; }
    const float* W1 = Wl;
    const float* W2 = Wl + NODE_DIM * 256;
    for (int k = 0; k < NODE_DIM; k++) {
        float w1 = W1[k * 256 + t];
        float w2 = W2[k * 256 + t];
#pragma unroll
        for (int jj = 0; jj < NPB2; jj += 4) {
            float4 xj = *(const float4*)&xs[k * NPB2 + jj];
            a1[jj + 0] = fmaf(w1, xj.x, a1[jj + 0]);
            a1[jj + 1] = fmaf(w1, xj.y, a1[jj + 1]);
            a1[jj + 2] = fmaf(w1, xj.z, a1[jj + 2]);
            a1[jj + 3] = fmaf(w1, xj.w, a1[jj + 3]);
            a2[jj + 0] = fmaf(w2, xj.x, a2[jj + 0]);
            a2[jj + 1] = fmaf(w2, xj.y, a2[jj + 1]);
            a2[jj + 2] = fmaf(w2, xj.z, a2[jj + 2]);
            a2[jj + 3] = fmaf(w2, xj.w, a2[jj + 3]);
        }
    }
    float bb = bl[t];
#pragma unroll
    for (int j = 0; j < NPB2; j++) {
        P1[(base + j) * 256 + t] = a1[j] + bb;
        P2[(base + j) * 256 + t] = a2[j];
    }
}

// ---------------------------------------------------------------- edge msg v4
// dst-sorted edges, 256/block in 8 chunks of 32. Sparse 10-tap window, bf16 We
// in LDS, fast softplus epilogue, 3 barriers/chunk, segmented-reduce + atomics.
#define NT 10
#define EG2 32
#define EPB 256
__global__ __launch_bounds__(256, 2) void edge_fused3(
    const int* __restrict__ s_src, const int* __restrict__ s_dst,
    const float* __restrict__ s_d,
    const float* __restrict__ P1, const float* __restrict__ P2,
    const __hip_bfloat16* __restrict__ Webf, float* __restrict__ agg) {
    __shared__ __hip_bfloat16 WeL[EDGE_DIM * 256];  // 51200 B
    __shared__ float msgL[EG2 * 128];               // 16384 B
    __shared__ float eaL[EG2 * NT];                 // 1280 B
    __shared__ int dstL[EG2];
    int t = threadIdx.x;
    {  // stage We once: 3200 x 16B
        const float4* s4 = (const float4*)Webf;
        float4* d4 = (float4*)WeL;
        for (int i = t; i < 3200; i += 256) d4[i] = s4[i];
    }
    const float sp_ = 6.0f / 99.0f;
    const float inv_s = 99.0f / 6.0f;
    const float coeff = -0.5f * inv_s * inv_s;
    int w = t >> 6, lane = t & 63, h = lane >> 5, q = lane & 31;
    int base0 = blockIdx.x * EPB;
    for (int base = base0; base < base0 + EPB; base += EG2) {
        __syncthreads();  // WeL staged (1st) / prev chunk msgL+eaL readers done
        // phase 1: taps + dst broadcast list
        if (t < EG2) dstL[t] = s_dst[base + t];
        for (int idx = t; idx < EG2 * NT; idx += 256) {
            int j = idx / NT, i = idx - j * NT;
            float dv = s_d[base + j];
            float v = 0.f;
            if (dv <= 6.34f) {
                int k0 = max(0, min(EDGE_DIM - NT, (int)ceilf(dv * inv_s - 4.5f)));
                float df = dv - (float)(k0 + i) * sp_;
                v = __expf(coeff * df * df);
            }
            eaL[idx] = v;
        }
        // per-lane meta + gather (4 consecutive edges)
        int e0 = base + w * 8 + h * 4;
        float4 a1[4], a2[4];
        int ds_[4], k0_[4];
#pragma unroll
        for (int mm = 0; mm < 4; mm++) {
            int sc = s_src[e0 + mm];
            int dd = s_dst[e0 + mm];
            float dv = s_d[e0 + mm];
            ds_[mm] = dd;
            k0_[mm] = (dv > 6.34f) ? -1
                      : max(0, min(EDGE_DIM - NT, (int)ceilf(dv * inv_s - 4.5f)));
            const float4* p1 = (const float4*)&P1[(size_t)dd * 256];
            const float4* p2 = (const float4*)&P2[(size_t)sc * 256];
            float4 p1a = p1[q], p1b = p1[32 + q];
            float4 p2a = p2[q], p2b = p2[32 + q];
            a1[mm] = make_float4(p1a.x + p2a.x, p1a.y + p2a.y, p1a.z + p2a.z, p1a.w + p2a.w);
            a2[mm] = make_float4(p1b.x + p2b.x, p1b.y + p2b.y, p1b.z + p2b.z, p1b.w + p2b.w);
        }
        __syncthreads();  // eaL ready
        // sparse taps
#pragma unroll
        for (int mm = 0; mm < 4; mm++) {
            int j = w * 8 + h * 4 + mm;
            int k0 = k0_[mm];
            if (k0 >= 0) {
#pragma unroll
                for (int i = 0; i < NT; i++) {
                    float e = eaL[j * NT + i];
                    const uint2* row = (const uint2*)&WeL[(k0 + i) * 256];
                    uint2 u1 = row[q];
                    uint2 u2 = row[32 + q];
                    a1[mm].x = fmaf(__uint_as_float(u1.x << 16), e, a1[mm].x);
                    a1[mm].y = fmaf(__uint_as_float(u1.x & 0xffff0000u), e, a1[mm].y);
                    a1[mm].z = fmaf(__uint_as_float(u1.y << 16), e, a1[mm].z);
                    a1[mm].w = fmaf(__uint_as_float(u1.y & 0xffff0000u), e, a1[mm].w);
                    a2[mm].x = fmaf(__uint_as_float(u2.x << 16), e, a2[mm].x);
                    a2[mm].y = fmaf(__uint_as_float(u2.x & 0xffff0000u), e, a2[mm].y);
                    a2[mm].z = fmaf(__uint_as_float(u2.y << 16), e, a2[mm].z);
                    a2[mm].w = fmaf(__uint_as_float(u2.y & 0xffff0000u), e, a2[mm].w);
                }
            }
        }
        // epilogue -> msgL
#pragma unroll
        for (int mm = 0; mm < 4; mm++) {
            int j = w * 8 + h * 4 + mm;
            float4 z1 = a1[mm], z2 = a2[mm], mg;
            mg.x = sigmoid_f(z1.x) * softplus_f(z2.x);
            mg.y = sigmoid_f(z1.y) * softplus_f(z2.y);
            mg.z = sigmoid_f(z1.z) * softplus_f(z2.z);
            mg.w = sigmoid_f(z1.w) * softplus_f(z2.w);
            *(float4*)&msgL[j * 128 + 4 * q] = mg;
        }
        __syncthreads();  // msgL ready
        // segmented reduce: thread = (channel c, edge half)
        int c = t & 127, eb = (t >> 7) * 16, ee = eb + 16;
        float run = 0.f;
        int cur = -1;
        for (int e = eb; e < ee; e++) {
            int dd = dstL[e];
            float v = msgL[e * 128 + c];
            if (dd != cur) {
                if (cur >= 0) atomicAdd(&agg[(size_t)cur * NODE_DIM + c], run);
                run = 0.f;
                cur = dd;
            }
            run += v;
        }
        if (cur >= 0) atomicAdd(&agg[(size_t)cur * NODE_DIM + c], run);
    }
}

// ---------------------------------------------------------------- layernorm + residual + softplus
__global__ void ln_kernel(const float* __restrict__ agg, const float* __restrict__ g,
                          const float* __restrict__ b, float* __restrict__ x) {
    int n = blockIdx.x, c = threadIdx.x;
    __shared__ float s1[128], s2[128];
    float a = agg[n * 128 + c];
    s1[c] = a;
    s2[c] = a * a;
    __syncthreads();
    for (int off = 64; off > 0; off >>= 1) {
        if (c < off) { s1[c] += s1[c + off]; s2[c] += s2[c + off]; }
        __syncthreads();
    }
    float mu = s1[0] * (1.0f / 128.0f);
    float var = s2[0] * (1.0f / 128.0f) - mu * mu;
    float rstd = rsqrtf(fmaxf(var, 0.f) + 1e-5f);
    float xv = x[n * 128 + c];
    x[n * 128 + c] = softplus_f((a - mu) * rstd * g[c] + b[c] + xv);
}

// ---------------------------------------------------------------- global mean pool
__global__ void pool_kernel(const float* __restrict__ x, const int* __restrict__ batch,
                            float* __restrict__ mol, float* __restrict__ cnt) {
    int i = blockIdx.x * blockDim.x + threadIdx.x;
    if (i >= N_NODES * 128) return;
    int n = i >> 7, c = i & 127;
    int g = batch[n];
    atomicAdd(&mol[g * 128 + c], x[i]);
    if (c == 0) atomicAdd(&cnt[g], 1.0f);
}

// ---------------------------------------------------------------- MLP head
__global__ void head_kernel(const float* __restrict__ mol, const float* __restrict__ cnt,
                            const float* __restrict__ cfc_w, const float* __restrict__ cfc_b,
                            const float* __restrict__ fc_w, const float* __restrict__ fc_b,
                            const float* __restrict__ out_w, const float* __restrict__ out_b,
                            float* __restrict__ out) {
    int g = blockIdx.x, c = threadIdx.x;
    __shared__ float h[128], h2[128];
    float denom = fmaxf(cnt[g], 1.0f);
    h[c] = mol[g * 128 + c] / denom;
    __syncthreads();
    float acc = cfc_b[c];
    for (int k = 0; k < 128; k++) acc = fmaf(h[k], cfc_w[k * 128 + c], acc);
    h2[c] = softplus_f(acc);
    __syncthreads();
    for (int l = 0; l < 2; l++) {
        const float* W = fc_w + l * 128 * 128;
        acc = fc_b[l * 128 + c];
        for (int k = 0; k < 128; k++) acc = fmaf(h2[k], W[k * 128 + c], acc);
        __syncthreads();
        h2[c] = softplus_f(acc);
        __syncthreads();
    }
    h[c] = h2[c] * out_w[c];
    __syncthreads();
    for (int off = 64; off > 0; off >>= 1) {
        if (c < off) h[c] += h[c + off];
        __syncthreads();
    }
    if (c == 0) out[g] = h[0] + out_b[0];
}

// ---------------------------------------------------------------- launcher
extern "C" void kernel_launch(void* const* d_in, const int* in_sizes, int n_in,
                              void* d_out, int out_size, void* d_ws, size_t ws_size,
                              hipStream_t stream) {
    const int*   z      = (const int*)d_in[0];
    const float* R      = (const float*)d_in[1];
    const int*   ei     = (const int*)d_in[2];
    const int*   batch  = (const int*)d_in[3];
    const float* emb    = (const float*)d_in[4];
    const float* emb_w  = (const float*)d_in[5];
    const float* emb_b  = (const float*)d_in[6];
    const float* conv_w = (const float*)d_in[7];
    const float* conv_b = (const float*)d_in[8];
    const float* ln_g   = (const float*)d_in[9];
    const float* ln_b   = (const float*)d_in[10];
    const float* cfc_w  = (const float*)d_in[11];
    const float* cfc_b  = (const float*)d_in[12];
    const float* fc_w   = (const float*)d_in[13];
    const float* fc_b   = (const float*)d_in[14];
    const float* out_w  = (const float*)d_in[15];
    const float* out_b  = (const float*)d_in[16];
    float* out = (float*)d_out;

    float* ws    = (float*)d_ws;
    float* dbuf  = ws;                    // 800,000
    float* x     = dbuf + 800000;         // 6,400,000
    float* agg   = x + 6400000;           // 6,400,000
    float* P1    = agg + 6400000;         // 12,800,000
    float* P2    = P1 + 12800000;         // 12,800,000
    float* mol   = P2 + 12800000;         // 32,768
    float* cntv  = mol + 32768;           // 256
    float* s_d   = cntv + 256;            // 800,000
    int* deg     = (int*)(s_d + 800000);  // 50,000
    int* cnt2    = deg + 50000;           // 50,000
    int* row_ptr = cnt2 + 50000;          // 50,001
    int* s_src   = row_ptr + 50001;       // 800,000
    int* s_dst   = s_src + 800000;        // 800,000
    int* bsum    = s_dst + 800000;        // 64
    __hip_bfloat16* Webf = (__hip_bfloat16*)(bsum + 64);  // 76,800 bf16

    edge_d_kernel<<<(N_EDGES + 255) / 256, 256, 0, stream>>>(ei, R, dbuf);
    hipMemsetAsync(deg, 0, (size_t)100000 * 4, stream);
    deg_kernel<<<(N_EDGES + 255) / 256, 256, 0, stream>>>(ei, deg);
    int nsb = (N_NODES + SB - 1) / SB;  // 49
    scan1_kernel<<<nsb, SB, 0, stream>>>(deg, row_ptr, bsum);
    scan2_kernel<<<1, 64, 0, stream>>>(bsum, nsb);
    scan3_kernel<<<nsb, SB, 0, stream>>>(row_ptr, bsum);
    fill_kernel<<<(N_EDGES + 255) / 256, 256, 0, stream>>>(ei, dbuf, row_ptr, cnt2,
                                                           s_src, s_dst, s_d);
    wcvt_kernel<<<(3 * EDGE_DIM * 256 + 255) / 256, 256, 0, stream>>>(conv_w, Webf);

    embed_kernel<<<N_NODES / 8, 128, 0, stream>>>(z, emb, emb_w, emb_b, x);
    int nblk = (N_EDGES + EPB - 1) / EPB;  // 3125
    for (int l = 0; l < 3; l++) {
        const float* Wl = conv_w + (size_t)l * 356 * 256;
        node_pre_kernel<<<N_NODES / NPB2, 256, 0, stream>>>(x, Wl, conv_b + l * 256, P1, P2);
        hipMemsetAsync(agg, 0, (size_t)6400000 * 4, stream);
        edge_fused3<<<nblk, 256, 0, stream>>>(s_src, s_dst, s_d, P1, P2,
                                              Webf + (size_t)l * EDGE_DIM * 256, agg);
        ln_kernel<<<N_NODES, 128, 0, stream>>>(agg, ln_g + l * 128, ln_b + l * 128, x);
    }
    hipMemsetAsync(mol, 0, (size_t)(32768 + 256) * 4, stream);
    pool_kernel<<<(N_NODES * 128 + 255) / 256, 256, 0, stream>>>(x, batch, mol, cntv);
    head_kernel<<<N_GRAPHS, 128, 0, stream>>>(mol, cntv, cfc_w, cfc_b, fc_w, fc_b,
                                              out_w, out_b, out);
}

// Round 5
// 1566.000 us; speedup vs baseline: 7.9212x; 1.0497x over previous
//
#include <hip/hip_runtime.h>
#include <hip/hip_bf16.h>
#include <cmath>

#define N_NODES 50000
#define N_EDGES 800000
#define NODE_DIM 128
#define EDGE_DIM 100
#define EMB_DIM 92
#define N_GRAPHS 256

__device__ __forceinline__ float softplus_f(float v) {
    return v > 20.0f ? v : __logf(1.0f + __expf(v));
}
__device__ __forceinline__ float sigmoid_f(float v) {
    return 1.0f / (1.0f + __expf(-v));
}

// ---------------------------------------------------------------- CSR build
__global__ void deg_kernel(const int* __restrict__ ei, int* __restrict__ deg) {
    int e = blockIdx.x * blockDim.x + threadIdx.x;
    if (e >= N_EDGES) return;
    atomicAdd(&deg[ei[N_EDGES + e]], 1);
}

#define SB 1024
__global__ void scan1_kernel(const int* __restrict__ deg, int* __restrict__ rp,
                             int* __restrict__ bsum) {
    __shared__ int buf[SB];
    int b = blockIdx.x, t = threadIdx.x, i = b * SB + t;
    int v = (i < N_NODES) ? deg[i] : 0;
    buf[t] = v;
    __syncthreads();
    for (int off = 1; off < SB; off <<= 1) {
        int a = (t >= off) ? buf[t - off] : 0;
        __syncthreads();
        buf[t] += a;
        __syncthreads();
    }
    if (i < N_NODES) rp[i] = buf[t] - v;
    if (t == SB - 1) bsum[b] = buf[t];
}
__global__ void scan2_kernel(int* __restrict__ bsum, int n) {
    if (threadIdx.x == 0) {
        int s = 0;
        for (int i = 0; i < n; i++) { int v = bsum[i]; bsum[i] = s; s += v; }
    }
}
__global__ void scan3_kernel(int* __restrict__ rp, const int* __restrict__ bsum) {
    int i = blockIdx.x * SB + threadIdx.x;
    if (i < N_NODES) rp[i] += bsum[blockIdx.x];
    if (i == 0) rp[N_NODES] = N_EDGES;
}

// fill CSR slots; distance computed inline (edge_d fused away)
__global__ void fill_kernel(const int* __restrict__ ei, const float* __restrict__ R,
                            const int* __restrict__ row_ptr, int* __restrict__ cnt2,
                            int* __restrict__ s_src, int* __restrict__ s_dst,
                            float* __restrict__ s_d) {
    int e = blockIdx.x * blockDim.x + threadIdx.x;
    if (e >= N_EDGES) return;
    int s = ei[e];
    int dst = ei[N_EDGES + e];
    float dx = R[3 * s + 0] - R[3 * dst + 0];
    float dy = R[3 * s + 1] - R[3 * dst + 1];
    float dz = R[3 * s + 2] - R[3 * dst + 2];
    float d = sqrtf(dx * dx + dy * dy + dz * dz);
    int pos = row_ptr[dst] + atomicAdd(&cnt2[dst], 1);
    s_src[pos] = s;
    s_dst[pos] = dst;
    s_d[pos] = d;
}

// ---------------------------------------------------------------- graph boundaries (batch sorted)
// gs[g] = first node index with batch >= g; gs[256] = N_NODES.
__global__ void gb_kernel(const int* __restrict__ batch, int* __restrict__ gs) {
    int i = blockIdx.x * 256 + threadIdx.x;
    if (i > N_NODES) return;
    int b = (i < N_NODES) ? batch[i] : N_GRAPHS;
    int pb = (i == 0) ? -1 : batch[i - 1];
    for (int g = pb + 1; g <= b; g++) gs[g] = i;
}

// ---------------------------------------------------------------- We -> bf16
__global__ void wcvt_kernel(const float* __restrict__ conv_w, __hip_bfloat16* __restrict__ Webf) {
    int i = blockIdx.x * 256 + threadIdx.x;
    if (i >= 3 * EDGE_DIM * 256) return;
    int l = i / (EDGE_DIM * 256), r = i - l * (EDGE_DIM * 256);
    Webf[i] = (__hip_bfloat16)conv_w[(size_t)l * 356 * 256 + 256 * 256 + r];
}

// ---------------------------------------------------------------- embedding
__global__ void embed_kernel(const int* __restrict__ z, const float* __restrict__ emb,
                             const float* __restrict__ emb_w, const float* __restrict__ emb_b,
                             float* __restrict__ x) {
    __shared__ float er[EMB_DIM * 8];
    __shared__ int zi[8];
    int base = blockIdx.x * 8;
    int t = threadIdx.x;  // 0..127
    if (t < 8) zi[t] = z[base + t];
    __syncthreads();
    for (int idx = t; idx < EMB_DIM * 8; idx += 128) {
        int k = idx >> 3, j = idx & 7;
        er[idx] = emb[zi[j] * EMB_DIM + k];
    }
    __syncthreads();
    float acc[8];
    float bb = emb_b[t];
#pragma unroll
    for (int j = 0; j < 8; j++) acc[j] = bb;
    for (int k = 0; k < EMB_DIM; k++) {
        float w = emb_w[k * NODE_DIM + t];
        float4 ja = *(const float4*)&er[k * 8];
        float4 jb = *(const float4*)&er[k * 8 + 4];
        acc[0] = fmaf(w, ja.x, acc[0]); acc[1] = fmaf(w, ja.y, acc[1]);
        acc[2] = fmaf(w, ja.z, acc[2]); acc[3] = fmaf(w, ja.w, acc[3]);
        acc[4] = fmaf(w, jb.x, acc[4]); acc[5] = fmaf(w, jb.y, acc[5]);
        acc[6] = fmaf(w, jb.z, acc[6]); acc[7] = fmaf(w, jb.w, acc[7]);
    }
#pragma unroll
    for (int j = 0; j < 8; j++) x[(base + j) * NODE_DIM + t] = acc[j];
}

// ---------------------------------------------------------------- node pre-GEMM (16 nodes/block)
#define NPB2 16
__global__ __launch_bounds__(256) void node_pre_kernel(
    const float* __restrict__ x, const float* __restrict__ Wl,
    const float* __restrict__ bl, float* __restrict__ P1, float* __restrict__ P2) {
    __shared__ float xs[NODE_DIM * NPB2];
    int base = blockIdx.x * NPB2;
    int t = threadIdx.x;  // 0..255 output channel
    for (int idx = t; idx < NODE_DIM * NPB2; idx += 256) {
        int j = idx >> 7, k = idx & 127;
        xs[k * NPB2 + j] = x[(base + j) * NODE_DIM + k];
    }
    __syncthreads();
    float a1[NPB2], a2[NPB2];
#pragma unroll
    for (int j = 0; j < NPB2; j++) { a1[j] = 0.f; a2[j] = 0.f; }
    const float* W1 = Wl;
    const float* W2 = Wl + NODE_DIM * 256;
    for (int k = 0; k < NODE_DIM; k++) {
        float w1 = W1[k * 256 + t];
        float w2 = W2[k * 256 + t];
#pragma unroll
        for (int jj = 0; jj < NPB2; jj += 4) {
            float4 xj = *(const float4*)&xs[k * NPB2 + jj];
            a1[jj + 0] = fmaf(w1, xj.x, a1[jj + 0]);
            a1[jj + 1] = fmaf(w1, xj.y, a1[jj + 1]);
            a1[jj + 2] = fmaf(w1, xj.z, a1[jj + 2]);
            a1[jj + 3] = fmaf(w1, xj.w, a1[jj + 3]);
            a2[jj + 0] = fmaf(w2, xj.x, a2[jj + 0]);
            a2[jj + 1] = fmaf(w2, xj.y, a2[jj + 1]);
            a2[jj + 2] = fmaf(w2, xj.z, a2[jj + 2]);
            a2[jj + 3] = fmaf(w2, xj.w, a2[jj + 3]);
        }
    }
    float bb = bl[t];
#pragma unroll
    for (int j = 0; j < NPB2; j++) {
        P1[(base + j) * 256 + t] = a1[j] + bb;
        P2[(base + j) * 256 + t] = a2[j];
    }
}

// ---------------------------------------------------------------- edge msg v5: barrier-free
// Thread = (channel-quad q, 8 consecutive edges). In-lane 10-tap window, bf16 We in
// LDS (only LDS use -> 3 blocks/CU), in-register run merge over dst-sorted edges,
// fire-and-forget atomics. Single __syncthreads after We stage.
#define NT 10
#define EPB3 640  // edges per block; 1250 blocks * 640 = 800000
__global__ __launch_bounds__(256, 3) void edge_fused4(
    const int* __restrict__ s_src, const int* __restrict__ s_dst,
    const float* __restrict__ s_d,
    const float* __restrict__ P1, const float* __restrict__ P2,
    const __hip_bfloat16* __restrict__ Webf, float* __restrict__ agg) {
    __shared__ __hip_bfloat16 WeL[EDGE_DIM * 256];  // 51200 B
    int t = threadIdx.x;
    {
        const float4* s4 = (const float4*)Webf;
        float4* d4 = (float4*)WeL;
        for (int i = t; i < 3200; i += 256) d4[i] = s4[i];
    }
    __syncthreads();
    const float sp_ = 6.0f / 99.0f;
    const float inv_s = 99.0f / 6.0f;
    const float coeff = -0.5f * inv_s * inv_s;
    int q = t & 31;        // channel quad: z1 ch 4q..4q+3, z2 ch 128+4q..
    int grp = t >> 5;      // edge group 0..7
    int blk0 = blockIdx.x * EPB3;
    float4 run = make_float4(0.f, 0.f, 0.f, 0.f);
    int cur = -1;
    for (int base = blk0; base < blk0 + EPB3; base += 64) {
        int e0 = base + grp * 8;
#pragma unroll
        for (int half = 0; half < 2; half++) {
            int eh = e0 + half * 4;
            int4 sc4 = *(const int4*)&s_src[eh];
            int4 dd4 = *(const int4*)&s_dst[eh];
            float4 dv4 = *(const float4*)&s_d[eh];
            int scs[4] = {sc4.x, sc4.y, sc4.z, sc4.w};
            int dds[4] = {dd4.x, dd4.y, dd4.z, dd4.w};
            float dvs[4] = {dv4.x, dv4.y, dv4.z, dv4.w};
            float4 a1[4], a2[4];
#pragma unroll
            for (int m = 0; m < 4; m++) {
                const float4* p1 = (const float4*)&P1[(size_t)dds[m] * 256];
                const float4* p2 = (const float4*)&P2[(size_t)scs[m] * 256];
                float4 p1a = p1[q], p2a = p2[q];
                float4 p1b = p1[32 + q], p2b = p2[32 + q];
                a1[m] = make_float4(p1a.x + p2a.x, p1a.y + p2a.y, p1a.z + p2a.z, p1a.w + p2a.w);
                a2[m] = make_float4(p1b.x + p2b.x, p1b.y + p2b.y, p1b.z + p2b.z, p1b.w + p2b.w);
            }
            // in-lane sparse taps (skip for far edges: all taps < 3e-7)
#pragma unroll
            for (int m = 0; m < 4; m++) {
                float dv = dvs[m];
                if (dv <= 6.34f) {
                    int k0 = max(0, min(EDGE_DIM - NT, (int)ceilf(dv * inv_s - 4.5f)));
#pragma unroll
                    for (int i = 0; i < NT; i++) {
                        float df = dv - (float)(k0 + i) * sp_;
                        float e = __expf(coeff * df * df);
                        const uint2* row = (const uint2*)&WeL[(k0 + i) * 256];
                        uint2 u1 = row[q];
                        uint2 u2 = row[32 + q];
                        a1[m].x = fmaf(__uint_as_float(u1.x << 16), e, a1[m].x);
                        a1[m].y = fmaf(__uint_as_float(u1.x & 0xffff0000u), e, a1[m].y);
                        a1[m].z = fmaf(__uint_as_float(u1.y << 16), e, a1[m].z);
                        a1[m].w = fmaf(__uint_as_float(u1.y & 0xffff0000u), e, a1[m].w);
                        a2[m].x = fmaf(__uint_as_float(u2.x << 16), e, a2[m].x);
                        a2[m].y = fmaf(__uint_as_float(u2.x & 0xffff0000u), e, a2[m].y);
                        a2[m].z = fmaf(__uint_as_float(u2.y << 16), e, a2[m].z);
                        a2[m].w = fmaf(__uint_as_float(u2.y & 0xffff0000u), e, a2[m].w);
                    }
                }
            }
            // epilogue + run merge
#pragma unroll
            for (int m = 0; m < 4; m++) {
                float4 mg;
                mg.x = sigmoid_f(a1[m].x) * softplus_f(a2[m].x);
                mg.y = sigmoid_f(a1[m].y) * softplus_f(a2[m].y);
                mg.z = sigmoid_f(a1[m].z) * softplus_f(a2[m].z);
                mg.w = sigmoid_f(a1[m].w) * softplus_f(a2[m].w);
                if (dds[m] != cur) {
                    if (cur >= 0) {
                        float* ag = &agg[(size_t)cur * NODE_DIM + 4 * q];
                        atomicAdd(ag + 0, run.x);
                        atomicAdd(ag + 1, run.y);
                        atomicAdd(ag + 2, run.z);
                        atomicAdd(ag + 3, run.w);
                    }
                    cur = dds[m];
                    run = mg;
                } else {
                    run.x += mg.x; run.y += mg.y; run.z += mg.z; run.w += mg.w;
                }
            }
        }
    }
    if (cur >= 0) {
        float* ag = &agg[(size_t)cur * NODE_DIM + 4 * q];
        atomicAdd(ag + 0, run.x);
        atomicAdd(ag + 1, run.y);
        atomicAdd(ag + 2, run.z);
        atomicAdd(ag + 3, run.w);
    }
}

// ---------------------------------------------------------------- layernorm + residual + softplus
// 256 threads = 2 rows; wave-shuffle reduction, 1 barrier.
__global__ void ln_kernel(const float* __restrict__ agg, const float* __restrict__ g,
                          const float* __restrict__ b, float* __restrict__ x) {
    __shared__ float sm[4][2];
    int t = threadIdx.x;
    int r = blockIdx.x * 2 + (t >> 7);
    int c = t & 127;
    float a = agg[(size_t)r * 128 + c];
    float s1 = a, s2 = a * a;
#pragma unroll
    for (int off = 32; off > 0; off >>= 1) {
        s1 += __shfl_xor(s1, off);
        s2 += __shfl_xor(s2, off);
    }
    int wv = t >> 6;
    if ((t & 63) == 0) { sm[wv][0] = s1; sm[wv][1] = s2; }
    __syncthreads();
    int w0 = (t >> 7) * 2;
    float S1 = sm[w0][0] + sm[w0 + 1][0];
    float S2 = sm[w0][1] + sm[w0 + 1][1];
    float mu = S1 * (1.0f / 128.0f);
    float var = S2 * (1.0f / 128.0f) - mu * mu;
    float rstd = rsqrtf(fmaxf(var, 0.f) + 1e-5f);
    float xv = x[(size_t)r * 128 + c];
    x[(size_t)r * 128 + c] = softplus_f((a - mu) * rstd * g[c] + b[c] + xv);
}

// ---------------------------------------------------------------- fused mean-pool + MLP head
__global__ void pool_head_kernel(const float* __restrict__ x, const int* __restrict__ gs,
                                 const float* __restrict__ cfc_w, const float* __restrict__ cfc_b,
                                 const float* __restrict__ fc_w, const float* __restrict__ fc_b,
                                 const float* __restrict__ out_w, const float* __restrict__ out_b,
                                 float* __restrict__ out) {
    int g = blockIdx.x, c = threadIdx.x;  // 128 threads
    int n0 = gs[g], n1 = gs[g + 1];
    float s = 0.f;
    for (int n = n0; n < n1; n++) s += x[(size_t)n * 128 + c];
    __shared__ float h[128], h2[128];
    h[c] = s / fmaxf((float)(n1 - n0), 1.0f);
    __syncthreads();
    float acc = cfc_b[c];
    for (int k = 0; k < 128; k++) acc = fmaf(h[k], cfc_w[k * 128 + c], acc);
    h2[c] = softplus_f(acc);
    __syncthreads();
    for (int l = 0; l < 2; l++) {
        const float* W = fc_w + l * 128 * 128;
        acc = fc_b[l * 128 + c];
        for (int k = 0; k < 128; k++) acc = fmaf(h2[k], W[k * 128 + c], acc);
        __syncthreads();
        h2[c] = softplus_f(acc);
        __syncthreads();
    }
    h[c] = h2[c] * out_w[c];
    __syncthreads();
    for (int off = 64; off > 0; off >>= 1) {
        if (c < off) h[c] += h[c + off];
        __syncthreads();
    }
    if (c == 0) out[g] = h[0] + out_b[0];
}

// ---------------------------------------------------------------- launcher
extern "C" void kernel_launch(void* const* d_in, const int* in_sizes, int n_in,
                              void* d_out, int out_size, void* d_ws, size_t ws_size,
                              hipStream_t stream) {
    const int*   z      = (const int*)d_in[0];
    const float* R      = (const float*)d_in[1];
    const int*   ei     = (const int*)d_in[2];
    const int*   batch  = (const int*)d_in[3];
    const float* emb    = (const float*)d_in[4];
    const float* emb_w  = (const float*)d_in[5];
    const float* emb_b  = (const float*)d_in[6];
    const float* conv_w = (const float*)d_in[7];
    const float* conv_b = (const float*)d_in[8];
    const float* ln_g   = (const float*)d_in[9];
    const float* ln_b   = (const float*)d_in[10];
    const float* cfc_w  = (const float*)d_in[11];
    const float* cfc_b  = (const float*)d_in[12];
    const float* fc_w   = (const float*)d_in[13];
    const float* fc_b   = (const float*)d_in[14];
    const float* out_w  = (const float*)d_in[15];
    const float* out_b  = (const float*)d_in[16];
    float* out = (float*)d_out;

    float* ws    = (float*)d_ws;
    float* x     = ws;                     // 6,400,000
    float* agg   = x + 6400000;            // 6,400,000
    float* P1    = agg + 6400000;          // 12,800,000
    float* P2    = P1 + 12800000;          // 12,800,000
    float* s_d   = P2 + 12800000;          // 800,000
    int* s_src   = (int*)(s_d + 800000);   // 800,000
    int* s_dst   = s_src + 800000;         // 800,000
    int* row_ptr = s_dst + 800000;         // 50,004 (padded)
    int* deg     = row_ptr + 50004;        // 50,000
    int* cnt2    = deg + 50000;            // 50,000  (contiguous with deg for one memset)
    int* bsum    = cnt2 + 50000;           // 64
    int* gs      = bsum + 64;              // 260 (257 used, padded)
    __hip_bfloat16* Webf = (__hip_bfloat16*)(gs + 260);  // 76,800 bf16

    // CSR by dst (distance fused into fill)
    hipMemsetAsync(deg, 0, (size_t)100000 * 4, stream);  // deg + cnt2
    deg_kernel<<<(N_EDGES + 255) / 256, 256, 0, stream>>>(ei, deg);
    int nsb = (N_NODES + SB - 1) / SB;  // 49
    scan1_kernel<<<nsb, SB, 0, stream>>>(deg, row_ptr, bsum);
    scan2_kernel<<<1, 64, 0, stream>>>(bsum, nsb);
    scan3_kernel<<<nsb, SB, 0, stream>>>(row_ptr, bsum);
    fill_kernel<<<(N_EDGES + 255) / 256, 256, 0, stream>>>(ei, R, row_ptr, cnt2,
                                                           s_src, s_dst, s_d);
    gb_kernel<<<(N_NODES + 256) / 256 + 1, 256, 0, stream>>>(batch, gs);
    wcvt_kernel<<<(3 * EDGE_DIM * 256 + 255) / 256, 256, 0, stream>>>(conv_w, Webf);

    embed_kernel<<<N_NODES / 8, 128, 0, stream>>>(z, emb, emb_w, emb_b, x);
    for (int l = 0; l < 3; l++) {
        const float* Wl = conv_w + (size_t)l * 356 * 256;
        node_pre_kernel<<<N_NODES / NPB2, 256, 0, stream>>>(x, Wl, conv_b + l * 256, P1, P2);
        hipMemsetAsync(agg, 0, (size_t)6400000 * 4, stream);
        edge_fused4<<<N_EDGES / EPB3, 256, 0, stream>>>(s_src, s_dst, s_d, P1, P2,
                                                        Webf + (size_t)l * EDGE_DIM * 256, agg);
        ln_kernel<<<N_NODES / 2, 256, 0, stream>>>(agg, ln_g + l * 128, ln_b + l * 128, x);
    }
    pool_head_kernel<<<N_GRAPHS, 128, 0, stream>>>(x, gs, cfc_w, cfc_b, fc_w, fc_b,
                                                   out_w, out_b, out);
}